// Round 5
// baseline (4130.267 us; speedup 1.0000x reference)
//
#include <hip/hip_runtime.h>
#include <stdint.h>

#define Bv 64
#define Tv 512
#define Dv 256
#define Uv 512
#define WPG 32   // workgroups per row-group; each owns 16 u-cols x 3 gates

typedef __attribute__((ext_vector_type(8))) __bf16 bf16x8;
typedef __attribute__((ext_vector_type(8))) short short8;
typedef __attribute__((ext_vector_type(4))) float f32x4;

// Persistent device globals (zero at module load; never poisoned by harness).
// g_hbuf: double-buffered h exchange. One u64 per element:
//   (epoch32 << 32) | (bf16hi << 16) | bf16lo
// epoch = (gen-1)*512 + t + 1  (monotonic across launches -> graph-replay safe).
// The 8B store is naturally atomic: epoch and data cannot tear. The store IS
// the flag -> no drain, no flag lines, no hot-line polling contention.
// Ring safety (2 slots): a WG publishes step t only after ALL its threads'
// (t-1)-gathers matched (unpack -> __syncthreads -> MFMA -> epilogue), so a
// slot is never overwritten before every dependent reader consumed it.
__device__ unsigned long long g_hbuf[2 * Bv * Uv];   // 512 KB
__device__ unsigned int g_gen[4 * WPG];

__device__ __forceinline__ unsigned int f2bf_bits(float x) {
    unsigned int u = __float_as_uint(x);
    return (u + 0x7fffu + ((u >> 16) & 1u)) >> 16;   // RNE to bf16
}
__device__ __forceinline__ float bfbits2f(unsigned int b) {
    return __uint_as_float(b << 16);
}
__device__ __forceinline__ float fast_sigmoid(float x) {
    return __builtin_amdgcn_rcpf(1.f + __expf(-x));
}
__device__ __forceinline__ float fast_tanh(float x) {
    float ax = fabsf(x);
    float t  = __expf(-2.f * ax);
    float r  = (1.f - t) * __builtin_amdgcn_rcpf(1.f + t);
    return x < 0.f ? -r : r;
}

extern "C" __global__ void __launch_bounds__(256, 1)
noglstm_kernel(const float* __restrict__ x,
               const float* __restrict__ w_xi, const float* __restrict__ w_xf, const float* __restrict__ w_xc,
               const float* __restrict__ w_hi, const float* __restrict__ w_hf, const float* __restrict__ w_hc,
               const float* __restrict__ b_i, const float* __restrict__ b_f, const float* __restrict__ b_c,
               const float* __restrict__ h0, const float* __restrict__ c0,
               float* __restrict__ out)
{
    __shared__ uint4 hHi[16 * 64], hLo[16 * 64];       // 32 KB: h fragments hi/lo
    __shared__ uint4 xHi[2][8 * 64], xLo[2][8 * 64];   // 32 KB: x fragments, double-buffered
    __shared__ f32x4 partLds[12 * 64];                 // 12 KB: 4 waves x 3 gates
    __shared__ float cTile[256];                       // persistent c state [16r x 16u]
    __shared__ float biasLds[48];
    __shared__ unsigned int baseLds;

    const int tid  = threadIdx.x;
    const int wg   = blockIdx.x;
    const int g    = wg >> 5;          // row group 0..3 (16 batch rows)
    const int c    = wg & 31;          // producer index within group
    const int r0   = g * 16;
    const int u0   = c * 16;
    const int wv   = tid >> 6;         // wave 0..3 = k-quarter
    const int lane = tid & 63;
    const int n    = lane & 15;
    const int quad = lane >> 4;
    const int kh   = wv;

    if (tid == 0) { unsigned v = g_gen[wg] + 1u; g_gen[wg] = v; baseLds = (v - 1u) * (unsigned)Tv; }
    if (tid < 16)      biasLds[tid] = b_i[u0 + tid];
    else if (tid < 32) biasLds[tid] = b_f[u0 + tid - 16];
    else if (tid < 48) biasLds[tid] = b_c[u0 + tid - 32];
    cTile[tid] = c0[(size_t)(r0 + (tid >> 4)) * Uv + u0 + (tid & 15)];

    // ---- W fragments: registers, bf16 hi/lo split, gathered once ----
    const float* WhP[3] = {w_hi, w_hf, w_hc};
    const float* WxP[3] = {w_xi, w_xf, w_xc};
    const int ucol = u0 + n;

    bf16x8 whHiR[3][4], whLoR[3][4], wxHiR[3][2], wxLoR[3][2];
    #pragma unroll
    for (int nt = 0; nt < 3; ++nt) {
        #pragma unroll
        for (int i = 0; i < 4; ++i) {
            short8 hi8, lo8;
            #pragma unroll
            for (int e = 0; e < 8; ++e) {
                int k = (kh * 4 + i) * 32 + quad * 8 + e;
                float w = WhP[nt][(size_t)k * Uv + ucol];
                unsigned int hb = f2bf_bits(w);
                unsigned int lb = f2bf_bits(w - bfbits2f(hb));
                hi8[e] = (short)hb; lo8[e] = (short)lb;
            }
            whHiR[nt][i] = __builtin_bit_cast(bf16x8, hi8);
            whLoR[nt][i] = __builtin_bit_cast(bf16x8, lo8);
        }
        #pragma unroll
        for (int i = 0; i < 2; ++i) {
            short8 hi8, lo8;
            #pragma unroll
            for (int e = 0; e < 8; ++e) {
                int k = (kh * 2 + i) * 32 + quad * 8 + e;
                float w = WxP[nt][(size_t)k * Uv + ucol];
                unsigned int hb = f2bf_bits(w);
                unsigned int lb = f2bf_bits(w - bfbits2f(hb));
                hi8[e] = (short)hb; lo8[e] = (short)lb;
            }
            wxHiR[nt][i] = __builtin_bit_cast(bf16x8, hi8);
            wxLoR[nt][i] = __builtin_bit_cast(bf16x8, lo8);
        }
    }

    auto stage8 = [&](const float* p, uint4* dHi, uint4* dLo) {
        f32x4 a = *(const f32x4*)p;
        f32x4 b = *(const f32x4*)(p + 4);
        float v[8] = {a[0], a[1], a[2], a[3], b[0], b[1], b[2], b[3]};
        unsigned int hb[8], lb[8];
        #pragma unroll
        for (int e = 0; e < 8; ++e) {
            hb[e] = f2bf_bits(v[e]);
            lb[e] = f2bf_bits(v[e] - bfbits2f(hb[e]));
        }
        *dHi = make_uint4(hb[0] | (hb[1] << 16), hb[2] | (hb[3] << 16),
                          hb[4] | (hb[5] << 16), hb[6] | (hb[7] << 16));
        *dLo = make_uint4(lb[0] | (lb[1] << 16), lb[2] | (lb[3] << 16),
                          lb[4] | (lb[5] << 16), lb[6] | (lb[7] << 16));
    };

    const int l = tid & 63, m = l & 15, q = l >> 4;

    // ---- preamble: stage x(0) into buffer 0 + h0 fragments ----
    #pragma unroll
    for (int i = 0; i < 2; ++i) {
        int u = tid + 256 * i;
        int kt = u >> 6, ll = u & 63, mm = ll & 15, qq = ll >> 4;
        const float* p = x + ((size_t)(r0 + mm) * Tv + 0) * Dv + kt * 32 + qq * 8;
        stage8(p, &xHi[0][kt * 64 + ll], &xLo[0][kt * 64 + ll]);
    }
    #pragma unroll
    for (int i = 0; i < 4; ++i) {
        int kt = wv + 4 * i;
        const float* p = h0 + (size_t)(r0 + m) * Uv + kt * 32 + q * 8;
        stage8(p, &hHi[kt * 64 + l], &hLo[kt * 64 + l]);
    }
    __syncthreads();

    const unsigned int base = baseLds;

    for (int t = 0; t < Tv; ++t) {
        const int p0 = t & 1;
        unsigned long long hw[32];
        const unsigned long long* hb = g_hbuf + (unsigned)((t - 1) & 1) * (Bv * Uv);
        const unsigned int E = base + (unsigned)t;   // expected epoch of h(t-1)

        // ---- first-pass gather: issue all 32 u64 loads, fully pipelined ----
        if (t > 0) {
            #pragma unroll
            for (int i = 0; i < 4; ++i) {
                int kt = wv + 4 * i;
                const unsigned long long* pp = hb + (r0 + m) * Uv + kt * 32 + q * 8;
                #pragma unroll
                for (int j = 0; j < 8; ++j)
                    hw[i * 8 + j] = __hip_atomic_load(pp + j, __ATOMIC_RELAXED,
                                                      __HIP_MEMORY_SCOPE_AGENT);
            }
        }

        // ---- x-part MFMA (buffer p0) overlaps the h gather latency ----
        f32x4 acc[3], accX[3];
        #pragma unroll
        for (int nt = 0; nt < 3; ++nt) { acc[nt] = f32x4{0.f,0.f,0.f,0.f}; accX[nt] = f32x4{0.f,0.f,0.f,0.f}; }
        #pragma unroll
        for (int i = 0; i < 2; ++i) {
            int kt = kh * 2 + i;
            bf16x8 aH = *(const bf16x8*)&xHi[p0][kt * 64 + lane];
            bf16x8 aL = *(const bf16x8*)&xLo[p0][kt * 64 + lane];
            #pragma unroll
            for (int nt = 0; nt < 3; ++nt) {
                accX[nt] = __builtin_amdgcn_mfma_f32_16x16x32_bf16(aH, wxHiR[nt][i], accX[nt], 0, 0, 0);
                accX[nt] = __builtin_amdgcn_mfma_f32_16x16x32_bf16(aH, wxLoR[nt][i], accX[nt], 0, 0, 0);
                accX[nt] = __builtin_amdgcn_mfma_f32_16x16x32_bf16(aL, wxHiR[nt][i], accX[nt], 0, 0, 0);
            }
        }

        // ---- stage x(t+1) into the other buffer: VALU fills h-load window ----
        if (t + 1 < Tv) {
            #pragma unroll
            for (int i = 0; i < 2; ++i) {
                int u = tid + 256 * i;
                int kt = u >> 6, ll = u & 63, mm = ll & 15, qq = ll >> 4;
                const float* p = x + ((size_t)(r0 + mm) * Tv + (t + 1)) * Dv + kt * 32 + qq * 8;
                stage8(p, &xHi[1 - p0][kt * 64 + ll], &xLo[1 - p0][kt * 64 + ll]);
            }
        }

        // ---- epoch check + per-tile retry, then unpack to LDS ----
        if (t > 0) {
            #pragma unroll
            for (int i = 0; i < 4; ++i) {
                int kt = wv + 4 * i;
                const unsigned long long* pp = hb + (r0 + m) * Uv + kt * 32 + q * 8;
                unsigned int spins = 0;
                for (;;) {
                    unsigned int stale = 0;
                    #pragma unroll
                    for (int j = 0; j < 8; ++j)
                        stale |= ((unsigned int)(hw[i * 8 + j] >> 32) != E) ? 1u : 0u;
                    if (!stale) break;
                    __builtin_amdgcn_s_sleep(1);
                    #pragma unroll
                    for (int j = 0; j < 8; ++j)
                        hw[i * 8 + j] = __hip_atomic_load(pp + j, __ATOMIC_RELAXED,
                                                          __HIP_MEMORY_SCOPE_AGENT);
                    if (++spins > (1u << 18)) break;   // bounded: fail loud, never hang
                }
                short8 hi8, lo8;
                #pragma unroll
                for (int j = 0; j < 8; ++j) {
                    unsigned int d0 = (unsigned int)hw[i * 8 + j];
                    hi8[j] = (short)(d0 >> 16);
                    lo8[j] = (short)(d0 & 0xffffu);
                }
                hHi[kt * 64 + l] = __builtin_bit_cast(uint4, hi8);
                hLo[kt * 64 + l] = __builtin_bit_cast(uint4, lo8);
            }
        }
        __syncthreads();   // B1: unpack/x-stage writes visible to all waves

        // ---- h-part MFMA: this wave's k-quarter, 3 gate columns ----
        #pragma unroll
        for (int i = 0; i < 4; ++i) {
            int kt = kh * 4 + i;
            bf16x8 aH = *(const bf16x8*)&hHi[kt * 64 + lane];
            bf16x8 aL = *(const bf16x8*)&hLo[kt * 64 + lane];
            #pragma unroll
            for (int nt = 0; nt < 3; ++nt) {
                acc[nt] = __builtin_amdgcn_mfma_f32_16x16x32_bf16(aH, whHiR[nt][i], acc[nt], 0, 0, 0);
                acc[nt] = __builtin_amdgcn_mfma_f32_16x16x32_bf16(aH, whLoR[nt][i], acc[nt], 0, 0, 0);
                acc[nt] = __builtin_amdgcn_mfma_f32_16x16x32_bf16(aL, whHiR[nt][i], acc[nt], 0, 0, 0);
            }
        }
        #pragma unroll
        for (int nt = 0; nt < 3; ++nt) {
            acc[nt][0] += accX[nt][0]; acc[nt][1] += accX[nt][1];
            acc[nt][2] += accX[nt][2]; acc[nt][3] += accX[nt][3];
            partLds[(wv * 3 + nt) * 64 + lane] = acc[nt];
        }
        __syncthreads();   // B2: partials visible to epilogue

        // ---- epilogue: one output element per thread; publish = data store ----
        {
            int r = tid >> 4, uu = tid & 15;
            int plane = (r >> 2) * 16 + uu;       // D layout: col=lane&15, row=quad*4+reg
            int reg = r & 3;
            const float* pf = (const float*)partLds;
            float pi = biasLds[uu], pF = biasLds[16 + uu], pc = biasLds[32 + uu];
            #pragma unroll
            for (int w = 0; w < 4; ++w) {
                pi += pf[((w * 3 + 0) * 64 + plane) * 4 + reg];
                pF += pf[((w * 3 + 1) * 64 + plane) * 4 + reg];
                pc += pf[((w * 3 + 2) * 64 + plane) * 4 + reg];
            }
            float iv  = fast_sigmoid(pi);
            float fv  = fast_sigmoid(pF);
            float cin = fast_tanh(pc);
            float cn  = fv * cTile[tid] + iv * cin;
            cTile[tid] = cn;
            float hn = fast_tanh(cn);
            unsigned int hbb = f2bf_bits(hn);
            unsigned int lbb = f2bf_bits(hn - bfbits2f(hbb));
            unsigned long long pub =
                ((unsigned long long)(base + (unsigned)t + 1u) << 32) | (hbb << 16) | lbb;
            __hip_atomic_store(g_hbuf + (unsigned)p0 * (Bv * Uv) + (r0 + r) * Uv + u0 + uu,
                               pub, __ATOMIC_RELAXED, __HIP_MEMORY_SCOPE_AGENT);
            out[((size_t)(r0 + r) * Tv + t) * Uv + u0 + uu] = hn;
        }
        // no loop-end barrier: B1/B2 of the next iteration provide all
        // cross-iteration LDS hazard separation (partLds: epilogue(t) reads
        // precede every thread's arrival at B1(t+1), writes follow it).
    }
}

extern "C" void kernel_launch(void* const* d_in, const int* in_sizes, int n_in,
                              void* d_out, int out_size, void* d_ws, size_t ws_size,
                              hipStream_t stream) {
    (void)in_sizes; (void)n_in; (void)out_size; (void)d_ws; (void)ws_size;
    noglstm_kernel<<<dim3(128), dim3(256), 0, stream>>>(
        (const float*)d_in[0],
        (const float*)d_in[1], (const float*)d_in[2], (const float*)d_in[3],
        (const float*)d_in[4], (const float*)d_in[5], (const float*)d_in[6],
        (const float*)d_in[7], (const float*)d_in[8], (const float*)d_in[9],
        (const float*)d_in[10], (const float*)d_in[11],
        (float*)d_out);
}